// Round 10
// baseline (222.187 us; speedup 1.0000x reference)
//
#include <hip/hip_runtime.h>

// ---------------------------------------------------------------------------
// MultiQueryAttention: out = softmax_causal((xWq+bq)(xWk+bk)^T * scale) (xWv+bv) Wo + bo
// B=2, S=2048, HIDDEN=2048, HEADS=16 (multi-query: 1 KV head), HEAD_DIM=128
// R9: R8 attn rewrite with the in-register type-punning fixed (bit_cast /
//     shufflevector instead of pointer punning into vector regs — TBAA-safe).
//     Zero-shuffle PV, tree max/sum, defer-max, scale folded into Wq/bq.
//     GEMMs unchanged (R7 8-wave dbuf).
// ---------------------------------------------------------------------------

#define HIDDEN 2048
#define NHEADS 16
#define HDIM 128
#define BATCH 2
#define SEQ 2048
// SCALE_QK * log2(e): softmax computed in base-2 (exp2); folded into Wq/bq.
#define SCALE_L2E 0.1275258653864023f

typedef __attribute__((ext_vector_type(8))) short bfrag;   // 8 bf16 (4 VGPRs)
typedef __attribute__((ext_vector_type(4))) short bhalf;   // 4 bf16 (8B)
typedef __attribute__((ext_vector_type(4))) float facc;    // MFMA accumulator
typedef __attribute__((ext_vector_type(4))) unsigned int uifrag;  // 4 u32 = 8 bf16

__device__ __forceinline__ unsigned short f2bf(float f) {  // f32 -> bf16 RNE
  unsigned int u = __float_as_uint(f);
  u += 0x7fffu + ((u >> 16) & 1u);
  return (unsigned short)(u >> 16);
}

// HW packed f32x2 -> bf16x2 (RNE); no builtin on gfx950, inline asm (T12).
__device__ __forceinline__ unsigned int cvt_pk_bf16(float lo, float hi) {
  unsigned int r;
  asm("v_cvt_pk_bf16_f32 %0, %1, %2" : "=v"(r) : "v"(lo), "v"(hi));
  return r;
}

// async global->LDS, 16B per lane. LDS dest is WAVE-UNIFORM base (+lane*16 by HW).
__device__ __forceinline__ void gl_lds16(const void* g, void* l) {
  __builtin_amdgcn_global_load_lds(
      (const __attribute__((address_space(1))) void*)g,
      (__attribute__((address_space(3))) void*)l, 16, 0, 0);
}

// ---------------------------------------------------------------------------
// x f32 -> bf16 (vectorized, HW cvt_pk)
__global__ __launch_bounds__(256) void cvt_bf16(const float* __restrict__ in,
                                                unsigned int* __restrict__ out, int n4) {
  int i = blockIdx.x * 256 + threadIdx.x;
  if (i >= n4) return;
  float4 v = ((const float4*)in)[i];
  uint2 o = {cvt_pk_bf16(v.x, v.y), cvt_pk_bf16(v.z, v.w)};
  ((uint2*)out)[i] = o;
}

// Two weights per launch (blockIdx.z picks): W [K][N] f32 -> WT [N][K] bf16,
// scaled by s0/s1 (used to fold the softmax scale into Wq).
__global__ __launch_bounds__(256) void transpose_cvt2(const float* __restrict__ W0,
                                                      short* __restrict__ T0,
                                                      const float* __restrict__ W1,
                                                      short* __restrict__ T1,
                                                      int K, int N,
                                                      float s0, float s1) {
  const float* W = blockIdx.z ? W1 : W0;
  short* WT = blockIdx.z ? T1 : T0;
  const float s = blockIdx.z ? s1 : s0;
  __shared__ float t[32][33];
  int tx = threadIdx.x & 31, ty = threadIdx.x >> 5;
  int n0 = blockIdx.x * 32, k0 = blockIdx.y * 32;
#pragma unroll
  for (int j = 0; j < 4; ++j)
    t[ty + j * 8][tx] = W[(size_t)(k0 + ty + j * 8) * N + n0 + tx];
  __syncthreads();
#pragma unroll
  for (int j = 0; j < 4; ++j)
    WT[(size_t)(n0 + ty + j * 8) * K + k0 + tx] = (short)f2bf(t[tx][ty + j * 8] * s);
}

// ---------------------------------------------------------------------------
// 8-wave 128x128 dbuf GEMM. 512 threads = 8 waves in 4M x 2N; per-wave C tile
// 32x64 (acc[2][4] frags). BK=64, double-buffered LDS (64KB -> 2 blocks/CU).
#define GEMM_STAGE8(buf, kt, A, BT, Kdim)                                      \
  _Pragma("unroll") for (int it_ = 0; it_ < 2; ++it_) {                        \
    int bc = (w * 2 + it_) * 64;                                               \
    int C = bc + l;                                                            \
    int row = C >> 3, c = C & 7;                                               \
    int gofs = (kt) * 64 + ((c ^ (row & 7)) << 3);                             \
    gl_lds16((A) + (size_t)(m0 + row) * (Kdim) + gofs, &Al[buf][bc * 8]);      \
    gl_lds16((BT) + (size_t)(n0 + row) * (Kdim) + gofs, &Bl[buf][bc * 8]);     \
  }

#define GEMM_PIPE_LOOP8(A, BT, Kdim)                                           \
  facc acc[2][4] = {};                                                         \
  const int nkt = (Kdim) >> 6;                                                 \
  GEMM_STAGE8(0, 0, A, BT, Kdim)                                               \
  __syncthreads();                                                             \
  for (int kt = 0; kt < nkt; ++kt) {                                           \
    const int cur = kt & 1;                                                    \
    if (kt + 1 < nkt) { GEMM_STAGE8(cur ^ 1, kt + 1, A, BT, Kdim) }            \
    __builtin_amdgcn_s_setprio(1);                                             \
    _Pragma("unroll") for (int ks = 0; ks < 2; ++ks) {                         \
      bfrag af[2], bf[4];                                                      \
      _Pragma("unroll") for (int mt = 0; mt < 2; ++mt) {                       \
        int row = wm * 32 + mt * 16 + l15;                                     \
        int c = ks * 4 + l4;                                                   \
        af[mt] = *(const bfrag*)&Al[cur][row * 64 + ((c ^ (row & 7)) << 3)];   \
      }                                                                        \
      _Pragma("unroll") for (int nt = 0; nt < 4; ++nt) {                       \
        int row = wn * 64 + nt * 16 + l15;                                     \
        int c = ks * 4 + l4;                                                   \
        bf[nt] = *(const bfrag*)&Bl[cur][row * 64 + ((c ^ (row & 7)) << 3)];   \
      }                                                                        \
      _Pragma("unroll") for (int mt = 0; mt < 2; ++mt)                         \
          _Pragma("unroll") for (int nt = 0; nt < 4; ++nt)                     \
              acc[mt][nt] = __builtin_amdgcn_mfma_f32_16x16x32_bf16(           \
                  af[mt], bf[nt], acc[mt][nt], 0, 0, 0);                       \
    }                                                                          \
    __builtin_amdgcn_s_setprio(0);                                             \
    __syncthreads();                                                           \
  }

// Fused QKV projection: BT = [Wq^T*scale; Wk^T; Wv^T] (2304 rows). Grid (32, 18).
__global__ __launch_bounds__(512, 4) void gemm_qkv(const short* __restrict__ A,
                                                   const short* __restrict__ BT,
                                                   const float* __restrict__ bq,
                                                   const float* __restrict__ bk,
                                                   const float* __restrict__ bv,
                                                   unsigned short* __restrict__ Qb,
                                                   unsigned short* __restrict__ Kb,
                                                   unsigned short* __restrict__ Vtb,
                                                   int M, int K) {
  __shared__ __align__(16) short Al[2][128 * 64];
  __shared__ __align__(16) short Bl[2][128 * 64];
  const int tid = threadIdx.x;
  const int w = tid >> 6, l = tid & 63;
  const int wm = w >> 1, wn = w & 1;
  const int l15 = l & 15, l4 = l >> 4;
  const int m0 = blockIdx.x * 128, n0 = blockIdx.y * 128;
  GEMM_PIPE_LOOP8(A, BT, K)
#pragma unroll
  for (int mt = 0; mt < 2; ++mt) {
#pragma unroll
    for (int nt = 0; nt < 4; ++nt) {
#pragma unroll
      for (int r = 0; r < 4; ++r) {
        int row = m0 + wm * 32 + mt * 16 + l4 * 4 + r;
        int col = n0 + wn * 64 + nt * 16 + l15;
        float v = acc[mt][nt][r];
        if (col < HIDDEN) {
          Qb[(size_t)row * HIDDEN + col] = f2bf(v + bq[col] * SCALE_L2E);
        } else if (col < HIDDEN + HDIM) {
          int lc = col - HIDDEN;
          Kb[(size_t)row * HDIM + lc] = f2bf(v + bk[lc]);
        } else {
          int lc = col - HIDDEN - HDIM;
          Vtb[(size_t)lc * M + row] = f2bf(v + bv[lc]);
        }
      }
    }
  }
}

// O-projection: f32 output C[row][col] = A*BT^T + bias. Grid (32, 16).
__global__ __launch_bounds__(512, 4) void gemm_out(const short* __restrict__ A,
                                                   const short* __restrict__ BT,
                                                   const float* __restrict__ bias,
                                                   float* __restrict__ Cout,
                                                   int M, int N, int K) {
  __shared__ __align__(16) short Al[2][128 * 64];
  __shared__ __align__(16) short Bl[2][128 * 64];
  const int tid = threadIdx.x;
  const int w = tid >> 6, l = tid & 63;
  const int wm = w >> 1, wn = w & 1;
  const int l15 = l & 15, l4 = l >> 4;
  const int m0 = blockIdx.x * 128, n0 = blockIdx.y * 128;
  GEMM_PIPE_LOOP8(A, BT, K)
#pragma unroll
  for (int mt = 0; mt < 2; ++mt)
#pragma unroll
    for (int nt = 0; nt < 4; ++nt)
#pragma unroll
      for (int r = 0; r < 4; ++r) {
        int row = m0 + wm * 32 + mt * 16 + l4 * 4 + r;
        int col = n0 + wn * 64 + nt * 16 + l15;
        Cout[(size_t)row * N + col] = acc[mt][nt][r] + bias[col];
      }
}

// ---------------------------------------------------------------------------
// Flash attention, swapped QK^T, causal-paired blocks, 4 waves x 16 q-rows.
// Grid: (16, HEADS, B) = 512 blocks, 256 threads, 64KB LDS -> 2 blocks/CU.
// Q pre-scaled by SCALE_QK*log2e. Zero-shuffle PV: keys within each K=32 MFMA
// chunk are permuted so slot g*8+j of chunk c = key (2c+(j>>2))*16+g*4+(j&3);
// lane (q=l15,g=l4) then feeds its OWN p-values as the A-fragment, and V
// fragments are two 8B LDS reads at 16B-chunks c*4+(l4>>1) and +2 (swizzled).
__global__ __launch_bounds__(256, 2) void attn_kernel(const short* __restrict__ Q,
                                                      const short* __restrict__ Kg,
                                                      const short* __restrict__ Vt,
                                                      unsigned short* __restrict__ O) {
  __shared__ __align__(16) short Kl[2][64 * 128];  // [buf][key][d] swizzled
  __shared__ __align__(16) short Vl[2][128 * 64];  // [buf][d][key] swizzled
  const int tid = threadIdx.x;
  const int w = tid >> 6, l = tid & 63;
  const int l15 = l & 15, l4 = l >> 4;
  const int h = blockIdx.y, b = blockIdx.z;

#define STAGE_KV(buf, t)                                                            \
  do {                                                                              \
    const int kv0_ = (t) << 6;                                                      \
    _Pragma("unroll") for (int it = 0; it < 4; ++it) {                              \
      int bc = (w * 4 + it) * 64;                                                   \
      int C = bc + l;                                                               \
      int key = C >> 4, c = C & 15;                                                 \
      gl_lds16(Kg + (size_t)(b * SEQ + kv0_ + key) * HDIM + ((c ^ (key & 7)) << 3), \
               &Kl[buf][bc * 8]);                                                   \
    }                                                                               \
    _Pragma("unroll") for (int it = 0; it < 4; ++it) {                              \
      int bc = (w * 4 + it) * 64;                                                   \
      int C = bc + l;                                                               \
      int d = C >> 3, c = C & 7;                                                    \
      gl_lds16(Vt + (size_t)d * (BATCH * SEQ) + b * SEQ + kv0_ + ((c ^ (d & 7)) << 3), \
               &Vl[buf][bc * 8]);                                                   \
    }                                                                               \
  } while (0)

  for (int pass = 0; pass < 2; ++pass) {
    const int qtile = (pass == 0) ? (int)blockIdx.x : 31 - (int)blockIdx.x;
    const int q0 = qtile * 64;
    const int qw = q0 + w * 16;  // this wave's 16 q-rows [qw, qw+16)

    // Q fragments (B-operand: col=q=l15, k contiguous): 4 k-chunks of 32
    bfrag aq[4];
#pragma unroll
    for (int kk = 0; kk < 4; ++kk)
      aq[kk] = *(const bfrag*)(Q + (size_t)(b * SEQ + qw + l15) * HIDDEN +
                               h * HDIM + kk * 32 + l4 * 8);

    facc accO[8] = {};
    float mrow = -INFINITY, lrow = 0.f;
    const int nkv = qtile + 1;

    STAGE_KV(0, 0);
    __syncthreads();

    for (int t = 0; t < nkv; ++t) {
      const int cur = t & 1;
      if (t + 1 < nkv) STAGE_KV(cur ^ 1, t + 1);
      const int kv0 = t << 6;

      // S^T = K * Q^T : A-frag = K (row=key=l15), B-frag = Q (col=q=l15).
      facc sac[4] = {};
      __builtin_amdgcn_s_setprio(1);
#pragma unroll
      for (int kk = 0; kk < 4; ++kk) {
        int c = kk * 4 + l4;
#pragma unroll
        for (int kt = 0; kt < 4; ++kt) {
          int key = kt * 16 + l15;
          bfrag ak = *(const bfrag*)&Kl[cur][key * 128 + ((c ^ (key & 7)) << 3)];
          sac[kt] = __builtin_amdgcn_mfma_f32_16x16x32_bf16(ak, aq[kk], sac[kt], 0, 0, 0);
        }
      }
      __builtin_amdgcn_s_setprio(0);

      // prefetch V fragments (latency hides under softmax). Two 8B reads per
      // fragment, combined via shufflevector (defined behavior, no punning):
      // halves at 16B-chunks cc = c*4+(l4>>1) and cc+2, intra-offset (l4&1)*4.
      bfrag bv[16];
#pragma unroll
      for (int c = 0; c < 2; ++c)
#pragma unroll
        for (int nt = 0; nt < 8; ++nt) {
          int d = nt * 16 + l15;
          int cc = c * 4 + (l4 >> 1);
          int base = d * 64 + (l4 & 1) * 4;
          bhalf lo = *(const bhalf*)&Vl[cur][base + ((cc ^ (d & 7)) << 3)];
          bhalf hi = *(const bhalf*)&Vl[cur][base + (((cc + 2) ^ (d & 7)) << 3)];
          bv[c * 8 + nt] = __builtin_shufflevector(lo, hi, 0, 1, 2, 3, 4, 5, 6, 7);
        }

      // online softmax (base-2, Q pre-scaled): lane holds 16 S for q = l15
      const int qg = qw + l15;
      const bool needmask = (kv0 + 63 > qw);
      float p[4][4];
#pragma unroll
      for (int kt = 0; kt < 4; ++kt)
#pragma unroll
        for (int r = 0; r < 4; ++r) {
          float v = sac[kt][r];
          if (needmask) {
            int keyg = kv0 + kt * 16 + l4 * 4 + r;
            v = (keyg <= qg) ? v : -INFINITY;
          }
          p[kt][r] = v;
        }
      // tree max (depth 4)
      float m0_ = fmaxf(fmaxf(p[0][0], p[0][1]), fmaxf(p[0][2], p[0][3]));
      float m1_ = fmaxf(fmaxf(p[1][0], p[1][1]), fmaxf(p[1][2], p[1][3]));
      float m2_ = fmaxf(fmaxf(p[2][0], p[2][1]), fmaxf(p[2][2], p[2][3]));
      float m3_ = fmaxf(fmaxf(p[3][0], p[3][1]), fmaxf(p[3][2], p[3][3]));
      float mt = fmaxf(fmaxf(m0_, m1_), fmaxf(m2_, m3_));
      mt = fmaxf(mt, __shfl_xor(mt, 16));
      mt = fmaxf(mt, __shfl_xor(mt, 32));
      // defer-max: rescale only when the running max grew by > 8 (log2)
      if (!__all(mt <= mrow + 8.0f)) {
        float mn = fmaxf(mrow, mt);
        float f = exp2f(mrow - mn);
        mrow = mn;
        lrow *= f;
        float fr[4];
#pragma unroll
        for (int r = 0; r < 4; ++r) fr[r] = __shfl(f, l4 * 4 + r);
#pragma unroll
        for (int nt = 0; nt < 8; ++nt)
#pragma unroll
          for (int r = 0; r < 4; ++r) accO[nt][r] *= fr[r];
      }
#pragma unroll
      for (int kt = 0; kt < 4; ++kt)
#pragma unroll
        for (int r = 0; r < 4; ++r) p[kt][r] = exp2f(p[kt][r] - mrow);
      // tree sum (depth 4)
      float s0_ = (p[0][0] + p[0][1]) + (p[0][2] + p[0][3]);
      float s1_ = (p[1][0] + p[1][1]) + (p[1][2] + p[1][3]);
      float s2_ = (p[2][0] + p[2][1]) + (p[2][2] + p[2][3]);
      float s3_ = (p[3][0] + p[3][1]) + (p[3][2] + p[3][3]);
      float ps = (s0_ + s1_) + (s2_ + s3_);
      ps += __shfl_xor(ps, 16);
      ps += __shfl_xor(ps, 32);
      lrow += ps;

      // PV (zero-shuffle): pa built in-register via bit_cast (TBAA-safe).
      // pa slots g*8+{0..3} = p[2c][0..3], {4..7} = p[2c+1][0..3].
      __builtin_amdgcn_s_setprio(1);
#pragma unroll
      for (int c = 0; c < 2; ++c) {
        uifrag up;
        up.x = cvt_pk_bf16(p[2 * c][0], p[2 * c][1]);
        up.y = cvt_pk_bf16(p[2 * c][2], p[2 * c][3]);
        up.z = cvt_pk_bf16(p[2 * c + 1][0], p[2 * c + 1][1]);
        up.w = cvt_pk_bf16(p[2 * c + 1][2], p[2 * c + 1][3]);
        bfrag pa = __builtin_bit_cast(bfrag, up);
#pragma unroll
        for (int nt = 0; nt < 8; ++nt)
          accO[nt] = __builtin_amdgcn_mfma_f32_16x16x32_bf16(pa, bv[c * 8 + nt],
                                                             accO[nt], 0, 0, 0);
      }
      __builtin_amdgcn_s_setprio(0);
      __syncthreads();
    }

    // epilogue: O rows q = l4*4+r, cols d = nt*16+l15
    float inv = 1.f / lrow;
#pragma unroll
    for (int r = 0; r < 4; ++r) {
      float invr = __shfl(inv, l4 * 4 + r);
      int row = qw + l4 * 4 + r;
#pragma unroll
      for (int nt = 0; nt < 8; ++nt)
        O[(size_t)(b * SEQ + row) * HIDDEN + h * HDIM + nt * 16 + l15] =
            f2bf(accO[nt][r] * invr);
    }
  }
#undef STAGE_KV
}

// ---------------------------------------------------------------------------
extern "C" void kernel_launch(void* const* d_in, const int* in_sizes, int n_in,
                              void* d_out, int out_size, void* d_ws, size_t ws_size,
                              hipStream_t stream) {
  const float* x = (const float*)d_in[0];
  // d_in[1] = mask (causal, applied analytically)
  const float* Wq = (const float*)d_in[2];
  const float* bq = (const float*)d_in[3];
  const float* Wk = (const float*)d_in[4];
  const float* bk = (const float*)d_in[5];
  const float* Wv = (const float*)d_in[6];
  const float* bv = (const float*)d_in[7];
  const float* Wo = (const float*)d_in[8];
  const float* bo = (const float*)d_in[9];
  float* out = (float*)d_out;

  const size_t MS = (size_t)BATCH * SEQ;  // 4096
  char* ws = (char*)d_ws;
  short* xb = (short*)ws;      ws += MS * HIDDEN * 2;
  short* WqkvT = (short*)ws;   ws += (size_t)(HIDDEN + 2 * HDIM) * HIDDEN * 2;  // 2304 rows
  short* WoT = (short*)ws;     ws += (size_t)HIDDEN * HIDDEN * 2;
  short* Qb = (short*)ws;      ws += MS * HIDDEN * 2;
  short* Kb = (short*)ws;      ws += MS * HDIM * 2;
  short* Vtb = (short*)ws;     ws += (size_t)HDIM * MS * 2;
  short* Ab = (short*)ws;      ws += MS * HIDDEN * 2;

  cvt_bf16<<<(int)(MS * HIDDEN / 4 / 256), 256, 0, stream>>>(
      x, (unsigned int*)xb, (int)(MS * HIDDEN / 4));
  transpose_cvt2<<<dim3(HIDDEN / 32, HIDDEN / 32, 2), 256, 0, stream>>>(
      Wq, WqkvT, Wo, WoT, HIDDEN, HIDDEN, SCALE_L2E, 1.0f);
  transpose_cvt2<<<dim3(HDIM / 32, HIDDEN / 32, 2), 256, 0, stream>>>(
      Wk, WqkvT + (size_t)HIDDEN * HIDDEN, Wv, WqkvT + (size_t)(HIDDEN + HDIM) * HIDDEN,
      HIDDEN, HDIM, 1.0f, 1.0f);

  gemm_qkv<<<dim3(32, 18), 512, 0, stream>>>(xb, WqkvT, bq, bk, bv,
                                             (unsigned short*)Qb, (unsigned short*)Kb,
                                             (unsigned short*)Vtb, (int)MS, HIDDEN);

  attn_kernel<<<dim3(16, NHEADS, BATCH), 256, 0, stream>>>(Qb, Kb, Vtb,
                                                           (unsigned short*)Ab);

  gemm_out<<<dim3(32, 16), 512, 0, stream>>>(Ab, WoT, bo, out, (int)MS, HIDDEN, HIDDEN);
}

// Round 11
// 205.839 us; speedup vs baseline: 1.0794x; 1.0794x over previous
//
#include <hip/hip_runtime.h>

// ---------------------------------------------------------------------------
// MultiQueryAttention: out = softmax_causal((xWq+bq)(xWk+bk)^T * scale) (xWv+bv) Wo + bo
// B=2, S=2048, HIDDEN=2048, HEADS=16 (multi-query: 1 KV head), HEAD_DIM=128
// R10: Vt stored PRE-PERMUTED per 64-row block (key 32c+16h+4g+r -> pos
//      32c+8g+4h+r) so zero-shuffle PV reads V as single ds_read_b128
//      (R9's dual-8B reads doubled bank conflicts). Rest of attn = R9.
//      GEMMs unchanged (R7 8-wave dbuf).
// ---------------------------------------------------------------------------

#define HIDDEN 2048
#define NHEADS 16
#define HDIM 128
#define BATCH 2
#define SEQ 2048
// SCALE_QK * log2(e): softmax computed in base-2 (exp2); folded into Wq/bq.
#define SCALE_L2E 0.1275258653864023f

typedef __attribute__((ext_vector_type(8))) short bfrag;   // 8 bf16 (4 VGPRs)
typedef __attribute__((ext_vector_type(4))) float facc;    // MFMA accumulator
typedef __attribute__((ext_vector_type(4))) unsigned int uifrag;  // 4 u32 = 8 bf16

__device__ __forceinline__ unsigned short f2bf(float f) {  // f32 -> bf16 RNE
  unsigned int u = __float_as_uint(f);
  u += 0x7fffu + ((u >> 16) & 1u);
  return (unsigned short)(u >> 16);
}

// HW packed f32x2 -> bf16x2 (RNE); no builtin on gfx950, inline asm (T12).
__device__ __forceinline__ unsigned int cvt_pk_bf16(float lo, float hi) {
  unsigned int r;
  asm("v_cvt_pk_bf16_f32 %0, %1, %2" : "=v"(r) : "v"(lo), "v"(hi));
  return r;
}

// async global->LDS, 16B per lane. LDS dest is WAVE-UNIFORM base (+lane*16 by HW).
__device__ __forceinline__ void gl_lds16(const void* g, void* l) {
  __builtin_amdgcn_global_load_lds(
      (const __attribute__((address_space(1))) void*)g,
      (__attribute__((address_space(3))) void*)l, 16, 0, 0);
}

// ---------------------------------------------------------------------------
// x f32 -> bf16 (vectorized, HW cvt_pk)
__global__ __launch_bounds__(256) void cvt_bf16(const float* __restrict__ in,
                                                unsigned int* __restrict__ out, int n4) {
  int i = blockIdx.x * 256 + threadIdx.x;
  if (i >= n4) return;
  float4 v = ((const float4*)in)[i];
  uint2 o = {cvt_pk_bf16(v.x, v.y), cvt_pk_bf16(v.z, v.w)};
  ((uint2*)out)[i] = o;
}

// Two weights per launch (blockIdx.z picks): W [K][N] f32 -> WT [N][K] bf16,
// scaled by s0/s1 (used to fold the softmax scale into Wq).
__global__ __launch_bounds__(256) void transpose_cvt2(const float* __restrict__ W0,
                                                      short* __restrict__ T0,
                                                      const float* __restrict__ W1,
                                                      short* __restrict__ T1,
                                                      int K, int N,
                                                      float s0, float s1) {
  const float* W = blockIdx.z ? W1 : W0;
  short* WT = blockIdx.z ? T1 : T0;
  const float s = blockIdx.z ? s1 : s0;
  __shared__ float t[32][33];
  int tx = threadIdx.x & 31, ty = threadIdx.x >> 5;
  int n0 = blockIdx.x * 32, k0 = blockIdx.y * 32;
#pragma unroll
  for (int j = 0; j < 4; ++j)
    t[ty + j * 8][tx] = W[(size_t)(k0 + ty + j * 8) * N + n0 + tx];
  __syncthreads();
#pragma unroll
  for (int j = 0; j < 4; ++j)
    WT[(size_t)(n0 + ty + j * 8) * K + k0 + tx] = (short)f2bf(t[tx][ty + j * 8] * s);
}

// ---------------------------------------------------------------------------
// 8-wave 128x128 dbuf GEMM. 512 threads = 8 waves in 4M x 2N; per-wave C tile
// 32x64 (acc[2][4] frags). BK=64, double-buffered LDS (64KB -> 2 blocks/CU).
#define GEMM_STAGE8(buf, kt, A, BT, Kdim)                                      \
  _Pragma("unroll") for (int it_ = 0; it_ < 2; ++it_) {                        \
    int bc = (w * 2 + it_) * 64;                                               \
    int C = bc + l;                                                            \
    int row = C >> 3, c = C & 7;                                               \
    int gofs = (kt) * 64 + ((c ^ (row & 7)) << 3);                             \
    gl_lds16((A) + (size_t)(m0 + row) * (Kdim) + gofs, &Al[buf][bc * 8]);      \
    gl_lds16((BT) + (size_t)(n0 + row) * (Kdim) + gofs, &Bl[buf][bc * 8]);     \
  }

#define GEMM_PIPE_LOOP8(A, BT, Kdim)                                           \
  facc acc[2][4] = {};                                                         \
  const int nkt = (Kdim) >> 6;                                                 \
  GEMM_STAGE8(0, 0, A, BT, Kdim)                                               \
  __syncthreads();                                                             \
  for (int kt = 0; kt < nkt; ++kt) {                                           \
    const int cur = kt & 1;                                                    \
    if (kt + 1 < nkt) { GEMM_STAGE8(cur ^ 1, kt + 1, A, BT, Kdim) }            \
    __builtin_amdgcn_s_setprio(1);                                             \
    _Pragma("unroll") for (int ks = 0; ks < 2; ++ks) {                         \
      bfrag af[2], bf[4];                                                      \
      _Pragma("unroll") for (int mt = 0; mt < 2; ++mt) {                       \
        int row = wm * 32 + mt * 16 + l15;                                     \
        int c = ks * 4 + l4;                                                   \
        af[mt] = *(const bfrag*)&Al[cur][row * 64 + ((c ^ (row & 7)) << 3)];   \
      }                                                                        \
      _Pragma("unroll") for (int nt = 0; nt < 4; ++nt) {                       \
        int row = wn * 64 + nt * 16 + l15;                                     \
        int c = ks * 4 + l4;                                                   \
        bf[nt] = *(const bfrag*)&Bl[cur][row * 64 + ((c ^ (row & 7)) << 3)];   \
      }                                                                        \
      _Pragma("unroll") for (int mt = 0; mt < 2; ++mt)                         \
          _Pragma("unroll") for (int nt = 0; nt < 4; ++nt)                     \
              acc[mt][nt] = __builtin_amdgcn_mfma_f32_16x16x32_bf16(           \
                  af[mt], bf[nt], acc[mt][nt], 0, 0, 0);                       \
    }                                                                          \
    __builtin_amdgcn_s_setprio(0);                                             \
    __syncthreads();                                                           \
  }

// PV-order permutation of a key index within its 64-block:
// key bits [c][h][g1g0][r1r0] -> pos bits [c][g1g0][h][r1r0].
__device__ __forceinline__ int pv_perm64(int row) {
  int k = row & 63;
  int p = (k & 0x23) | ((k & 0x0C) << 1) | ((k & 0x10) >> 2);
  return (row & ~63) | p;
}

// Fused QKV projection: BT = [Wq^T*scale; Wk^T; Wv^T] (2304 rows). Grid (32, 18).
// V^T rows (keys) are stored PV-permuted per 64-block (consumed only by attn).
__global__ __launch_bounds__(512, 4) void gemm_qkv(const short* __restrict__ A,
                                                   const short* __restrict__ BT,
                                                   const float* __restrict__ bq,
                                                   const float* __restrict__ bk,
                                                   const float* __restrict__ bv,
                                                   unsigned short* __restrict__ Qb,
                                                   unsigned short* __restrict__ Kb,
                                                   unsigned short* __restrict__ Vtb,
                                                   int M, int K) {
  __shared__ __align__(16) short Al[2][128 * 64];
  __shared__ __align__(16) short Bl[2][128 * 64];
  const int tid = threadIdx.x;
  const int w = tid >> 6, l = tid & 63;
  const int wm = w >> 1, wn = w & 1;
  const int l15 = l & 15, l4 = l >> 4;
  const int m0 = blockIdx.x * 128, n0 = blockIdx.y * 128;
  GEMM_PIPE_LOOP8(A, BT, K)
#pragma unroll
  for (int mt = 0; mt < 2; ++mt) {
#pragma unroll
    for (int nt = 0; nt < 4; ++nt) {
#pragma unroll
      for (int r = 0; r < 4; ++r) {
        int row = m0 + wm * 32 + mt * 16 + l4 * 4 + r;
        int col = n0 + wn * 64 + nt * 16 + l15;
        float v = acc[mt][nt][r];
        if (col < HIDDEN) {
          Qb[(size_t)row * HIDDEN + col] = f2bf(v + bq[col] * SCALE_L2E);
        } else if (col < HIDDEN + HDIM) {
          int lc = col - HIDDEN;
          Kb[(size_t)row * HDIM + lc] = f2bf(v + bk[lc]);
        } else {
          int lc = col - HIDDEN - HDIM;
          Vtb[(size_t)lc * M + pv_perm64(row)] = f2bf(v + bv[lc]);
        }
      }
    }
  }
}

// O-projection: f32 output C[row][col] = A*BT^T + bias. Grid (32, 16).
__global__ __launch_bounds__(512, 4) void gemm_out(const short* __restrict__ A,
                                                   const short* __restrict__ BT,
                                                   const float* __restrict__ bias,
                                                   float* __restrict__ Cout,
                                                   int M, int N, int K) {
  __shared__ __align__(16) short Al[2][128 * 64];
  __shared__ __align__(16) short Bl[2][128 * 64];
  const int tid = threadIdx.x;
  const int w = tid >> 6, l = tid & 63;
  const int wm = w >> 1, wn = w & 1;
  const int l15 = l & 15, l4 = l >> 4;
  const int m0 = blockIdx.x * 128, n0 = blockIdx.y * 128;
  GEMM_PIPE_LOOP8(A, BT, K)
#pragma unroll
  for (int mt = 0; mt < 2; ++mt)
#pragma unroll
    for (int nt = 0; nt < 4; ++nt)
#pragma unroll
      for (int r = 0; r < 4; ++r) {
        int row = m0 + wm * 32 + mt * 16 + l4 * 4 + r;
        int col = n0 + wn * 64 + nt * 16 + l15;
        Cout[(size_t)row * N + col] = acc[mt][nt][r] + bias[col];
      }
}

// ---------------------------------------------------------------------------
// Flash attention, swapped QK^T, causal-paired blocks, 4 waves x 16 q-rows.
// Grid: (16, HEADS, B) = 512 blocks, 256 threads, 64KB LDS -> 2 blocks/CU.
// Q pre-scaled by SCALE_QK*log2e. Zero-shuffle PV with PRE-PERMUTED Vt:
// lane (q=l15,g=l4) feeds its own p-values as the A-fragment; V fragment for
// chunk c is ONE ds_read_b128 at 16B-chunk (4c+g)^(d&7) of row d.
__global__ __launch_bounds__(256, 2) void attn_kernel(const short* __restrict__ Q,
                                                      const short* __restrict__ Kg,
                                                      const short* __restrict__ Vt,
                                                      unsigned short* __restrict__ O) {
  __shared__ __align__(16) short Kl[2][64 * 128];  // [buf][key][d] swizzled
  __shared__ __align__(16) short Vl[2][128 * 64];  // [buf][d][pos] swizzled
  const int tid = threadIdx.x;
  const int w = tid >> 6, l = tid & 63;
  const int l15 = l & 15, l4 = l >> 4;
  const int h = blockIdx.y, b = blockIdx.z;

#define STAGE_KV(buf, t)                                                            \
  do {                                                                              \
    const int kv0_ = (t) << 6;                                                      \
    _Pragma("unroll") for (int it = 0; it < 4; ++it) {                              \
      int bc = (w * 4 + it) * 64;                                                   \
      int C = bc + l;                                                               \
      int key = C >> 4, c = C & 15;                                                 \
      gl_lds16(Kg + (size_t)(b * SEQ + kv0_ + key) * HDIM + ((c ^ (key & 7)) << 3), \
               &Kl[buf][bc * 8]);                                                   \
    }                                                                               \
    _Pragma("unroll") for (int it = 0; it < 4; ++it) {                              \
      int bc = (w * 4 + it) * 64;                                                   \
      int C = bc + l;                                                               \
      int d = C >> 3, c = C & 7;                                                    \
      gl_lds16(Vt + (size_t)d * (BATCH * SEQ) + b * SEQ + kv0_ + ((c ^ (d & 7)) << 3), \
               &Vl[buf][bc * 8]);                                                   \
    }                                                                               \
  } while (0)

  for (int pass = 0; pass < 2; ++pass) {
    const int qtile = (pass == 0) ? (int)blockIdx.x : 31 - (int)blockIdx.x;
    const int q0 = qtile * 64;
    const int qw = q0 + w * 16;  // this wave's 16 q-rows [qw, qw+16)

    // Q fragments (B-operand: col=q=l15, k contiguous): 4 k-chunks of 32
    bfrag aq[4];
#pragma unroll
    for (int kk = 0; kk < 4; ++kk)
      aq[kk] = *(const bfrag*)(Q + (size_t)(b * SEQ + qw + l15) * HIDDEN +
                               h * HDIM + kk * 32 + l4 * 8);

    facc accO[8] = {};
    float mrow = -INFINITY, lrow = 0.f;
    const int nkv = qtile + 1;

    STAGE_KV(0, 0);
    __syncthreads();

    for (int t = 0; t < nkv; ++t) {
      const int cur = t & 1;
      if (t + 1 < nkv) STAGE_KV(cur ^ 1, t + 1);
      const int kv0 = t << 6;

      // S^T = K * Q^T : A-frag = K (row=key=l15), B-frag = Q (col=q=l15).
      facc sac[4] = {};
      __builtin_amdgcn_s_setprio(1);
#pragma unroll
      for (int kk = 0; kk < 4; ++kk) {
        int c = kk * 4 + l4;
#pragma unroll
        for (int kt = 0; kt < 4; ++kt) {
          int key = kt * 16 + l15;
          bfrag ak = *(const bfrag*)&Kl[cur][key * 128 + ((c ^ (key & 7)) << 3)];
          sac[kt] = __builtin_amdgcn_mfma_f32_16x16x32_bf16(ak, aq[kk], sac[kt], 0, 0, 0);
        }
      }
      __builtin_amdgcn_s_setprio(0);

      // prefetch V fragments (hide LDS latency under softmax): one b128 per
      // (c,nt); pre-permuted Vt makes chunk (4c+l4) hold this lane's 8 keys.
      bfrag bv[16];
#pragma unroll
      for (int c = 0; c < 2; ++c)
#pragma unroll
        for (int nt = 0; nt < 8; ++nt) {
          int d = nt * 16 + l15;
          int cc = c * 4 + l4;
          bv[c * 8 + nt] = *(const bfrag*)&Vl[cur][d * 64 + ((cc ^ (d & 7)) << 3)];
        }

      // online softmax (base-2, Q pre-scaled): lane holds 16 S for q = l15
      const int qg = qw + l15;
      const bool needmask = (kv0 + 63 > qw);
      float p[4][4];
#pragma unroll
      for (int kt = 0; kt < 4; ++kt)
#pragma unroll
        for (int r = 0; r < 4; ++r) {
          float v = sac[kt][r];
          if (needmask) {
            int keyg = kv0 + kt * 16 + l4 * 4 + r;
            v = (keyg <= qg) ? v : -INFINITY;
          }
          p[kt][r] = v;
        }
      // tree max (depth 4)
      float m0_ = fmaxf(fmaxf(p[0][0], p[0][1]), fmaxf(p[0][2], p[0][3]));
      float m1_ = fmaxf(fmaxf(p[1][0], p[1][1]), fmaxf(p[1][2], p[1][3]));
      float m2_ = fmaxf(fmaxf(p[2][0], p[2][1]), fmaxf(p[2][2], p[2][3]));
      float m3_ = fmaxf(fmaxf(p[3][0], p[3][1]), fmaxf(p[3][2], p[3][3]));
      float mt = fmaxf(fmaxf(m0_, m1_), fmaxf(m2_, m3_));
      mt = fmaxf(mt, __shfl_xor(mt, 16));
      mt = fmaxf(mt, __shfl_xor(mt, 32));
      // defer-max: rescale only when the running max grew by > 8 (log2)
      if (!__all(mt <= mrow + 8.0f)) {
        float mn = fmaxf(mrow, mt);
        float f = exp2f(mrow - mn);
        mrow = mn;
        lrow *= f;
        float fr[4];
#pragma unroll
        for (int r = 0; r < 4; ++r) fr[r] = __shfl(f, l4 * 4 + r);
#pragma unroll
        for (int nt = 0; nt < 8; ++nt)
#pragma unroll
          for (int r = 0; r < 4; ++r) accO[nt][r] *= fr[r];
      }
#pragma unroll
      for (int kt = 0; kt < 4; ++kt)
#pragma unroll
        for (int r = 0; r < 4; ++r) p[kt][r] = exp2f(p[kt][r] - mrow);
      // tree sum (depth 4)
      float s0_ = (p[0][0] + p[0][1]) + (p[0][2] + p[0][3]);
      float s1_ = (p[1][0] + p[1][1]) + (p[1][2] + p[1][3]);
      float s2_ = (p[2][0] + p[2][1]) + (p[2][2] + p[2][3]);
      float s3_ = (p[3][0] + p[3][1]) + (p[3][2] + p[3][3]);
      float ps = (s0_ + s1_) + (s2_ + s3_);
      ps += __shfl_xor(ps, 16);
      ps += __shfl_xor(ps, 32);
      lrow += ps;

      // PV (zero-shuffle): pa built in-register via bit_cast (TBAA-safe).
      // pa slots g*8+{0..3} = p[2c][0..3], {4..7} = p[2c+1][0..3].
      __builtin_amdgcn_s_setprio(1);
#pragma unroll
      for (int c = 0; c < 2; ++c) {
        uifrag up;
        up.x = cvt_pk_bf16(p[2 * c][0], p[2 * c][1]);
        up.y = cvt_pk_bf16(p[2 * c][2], p[2 * c][3]);
        up.z = cvt_pk_bf16(p[2 * c + 1][0], p[2 * c + 1][1]);
        up.w = cvt_pk_bf16(p[2 * c + 1][2], p[2 * c + 1][3]);
        bfrag pa = __builtin_bit_cast(bfrag, up);
#pragma unroll
        for (int nt = 0; nt < 8; ++nt)
          accO[nt] = __builtin_amdgcn_mfma_f32_16x16x32_bf16(pa, bv[c * 8 + nt],
                                                             accO[nt], 0, 0, 0);
      }
      __builtin_amdgcn_s_setprio(0);
      __syncthreads();
    }

    // epilogue: O rows q = l4*4+r, cols d = nt*16+l15
    float inv = 1.f / lrow;
#pragma unroll
    for (int r = 0; r < 4; ++r) {
      float invr = __shfl(inv, l4 * 4 + r);
      int row = qw + l4 * 4 + r;
#pragma unroll
      for (int nt = 0; nt < 8; ++nt)
        O[(size_t)(b * SEQ + row) * HIDDEN + h * HDIM + nt * 16 + l15] =
            f2bf(accO[nt][r] * invr);
    }
  }
#undef STAGE_KV
}

// ---------------------------------------------------------------------------
extern "C" void kernel_launch(void* const* d_in, const int* in_sizes, int n_in,
                              void* d_out, int out_size, void* d_ws, size_t ws_size,
                              hipStream_t stream) {
  const float* x = (const float*)d_in[0];
  // d_in[1] = mask (causal, applied analytically)
  const float* Wq = (const float*)d_in[2];
  const float* bq = (const float*)d_in[3];
  const float* Wk = (const float*)d_in[4];
  const float* bk = (const float*)d_in[5];
  const float* Wv = (const float*)d_in[6];
  const float* bv = (const float*)d_in[7];
  const float* Wo = (const float*)d_in[8];
  const float* bo = (const float*)d_in[9];
  float* out = (float*)d_out;

  const size_t MS = (size_t)BATCH * SEQ;  // 4096
  char* ws = (char*)d_ws;
  short* xb = (short*)ws;      ws += MS * HIDDEN * 2;
  short* WqkvT = (short*)ws;   ws += (size_t)(HIDDEN + 2 * HDIM) * HIDDEN * 2;  // 2304 rows
  short* WoT = (short*)ws;     ws += (size_t)HIDDEN * HIDDEN * 2;
  short* Qb = (short*)ws;      ws += MS * HIDDEN * 2;
  short* Kb = (short*)ws;      ws += MS * HDIM * 2;
  short* Vtb = (short*)ws;     ws += (size_t)HDIM * MS * 2;
  short* Ab = (short*)ws;      ws += MS * HIDDEN * 2;

  cvt_bf16<<<(int)(MS * HIDDEN / 4 / 256), 256, 0, stream>>>(
      x, (unsigned int*)xb, (int)(MS * HIDDEN / 4));
  transpose_cvt2<<<dim3(HIDDEN / 32, HIDDEN / 32, 2), 256, 0, stream>>>(
      Wq, WqkvT, Wo, WoT, HIDDEN, HIDDEN, SCALE_L2E, 1.0f);
  transpose_cvt2<<<dim3(HDIM / 32, HIDDEN / 32, 2), 256, 0, stream>>>(
      Wk, WqkvT + (size_t)HIDDEN * HIDDEN, Wv, WqkvT + (size_t)(HIDDEN + HDIM) * HIDDEN,
      HIDDEN, HDIM, 1.0f, 1.0f);

  gemm_qkv<<<dim3(32, 18), 512, 0, stream>>>(xb, WqkvT, bq, bk, bv,
                                             (unsigned short*)Qb, (unsigned short*)Kb,
                                             (unsigned short*)Vtb, (int)MS, HIDDEN);

  attn_kernel<<<dim3(16, NHEADS, BATCH), 256, 0, stream>>>(Qb, Kb, Vtb,
                                                           (unsigned short*)Ab);

  gemm_out<<<dim3(32, 16), 512, 0, stream>>>(Ab, WoT, bo, out, (int)MS, HIDDEN, HIDDEN);
}